// Round 15
// baseline (5348.305 us; speedup 1.0000x reference)
//
#include <hip/hip_runtime.h>
#include <cstdint>

// ---------------------------------------------------------------------------
// Threefry-2x32 (JAX partitionable-mode compatible), host + device.
// ---------------------------------------------------------------------------
__host__ __device__ inline uint32_t tf_rotl32(uint32_t x, uint32_t r) {
  return (x << r) | (x >> (32u - r));
}

__host__ __device__ inline void threefry2x32(uint32_t k0, uint32_t k1,
                                             uint32_t x0, uint32_t x1,
                                             uint32_t* o0, uint32_t* o1) {
  uint32_t ks0 = k0, ks1 = k1, ks2 = k0 ^ k1 ^ 0x1BD11BDAu;
  x0 += ks0; x1 += ks1;
#define TF_R(r) { x0 += x1; x1 = tf_rotl32(x1, r); x1 ^= x0; }
  TF_R(13) TF_R(15) TF_R(26) TF_R(6)
  x0 += ks1; x1 += ks2 + 1u;
  TF_R(17) TF_R(29) TF_R(16) TF_R(24)
  x0 += ks2; x1 += ks0 + 2u;
  TF_R(13) TF_R(15) TF_R(26) TF_R(6)
  x0 += ks0; x1 += ks1 + 3u;
  TF_R(17) TF_R(29) TF_R(16) TF_R(24)
  x0 += ks1; x1 += ks2 + 4u;
  TF_R(13) TF_R(15) TF_R(26) TF_R(6)
  x0 += ks2; x1 += ks0 + 5u;
#undef TF_R
  *o0 = x0; *o1 = x1;
}

// ---------------------------------------------------------------------------
// Problem dims
// ---------------------------------------------------------------------------
#define BSZ   8192
#define KIN   784
#define HID   800
#define NOUT  10
#define NSTEP 25

// R8: golden = Eigen gebp (AVX no-FMA jaxlib): k-panels [0,264) [264,528)
// [528,784), per k-step acc = rn(acc + rn(a*b)); C = 0.5*rn(rn(P0+P1)+P2).
// R9: a in {0,1,2} makes every product exact, so fmaf == mul+add bit-exactly.
// R17: panel-split -> occ 72%, gemm 158us (best).
// R20-R23 nulls: wall pinned 157-165us across 5 structures. Both pipes
//   ~122-125us simultaneously (pk_fma is HALF-RATE on CDNA4 = no gain over
//   fma; LDS 10 b128/tile-thread at data minimum). Must shrink BOTH pipes.
// R24 (this round): B-in-SGPRs. B values are wave-uniform (blockIdx, kk, c
//   only) -> lane computes 2 rows x ALL 32 cols; compiler scalarizes
//   w1t[(kstart+k)*HID+n0+c] into s_load_dwordx16; v_fmac_f32 v,s,v reads
//   1 SGPR (legal). Per kk-wave: 64 fmac + 2 cvt = 132 cyc per 4096 MACs
//   -> VALU ~67us (97% of fp32 FMA floor). A u8 row-major gload_lds; frag
//   = 2 contiguous b128/tile -> LDS ~6us. Zero __syncthreads (each wave
//   stages + reads only its own 128-row strip). w1 transposed once (w1t).
//   BM=512 (4 waves x 128 rows), grid 16x25x3 = 1200 blocks, all resident.
//   Tail (264=16x16+8): explicit 8-kk block. Bit-exact chains unchanged.
//   Predict gemm 158 -> 85-115us; falsifier >=150 -> scalarization failed.
// ---------------------------------------------------------------------------

// ---------------------------------------------------------------------------
// Kernel 1: Poisson encoding (JAX-faithful: truncated 2^-23 grid).
// enc = temp + 1 in {0,1,2}; sp = 0.5*enc (exact power-of-2 relation).
// ---------------------------------------------------------------------------
__global__ __launch_bounds__(256) void enc_kernel(const float* __restrict__ inp,
                                                  uint8_t* __restrict__ enc,
                                                  uint32_t k0, uint32_t k1) {
  int j = blockIdx.x * blockDim.x + threadIdx.x;
  if (j >= BSZ * KIN) return;
  uint32_t o0, o1;
  threefry2x32(k0, k1, 0u, (uint32_t)j, &o0, &o1);
  uint32_t bits = o0 ^ o1;
  float r = __uint_as_float((bits >> 9) | 0x3f800000u) - 1.0f;
  float x = inp[j];
  bool cond = (2.0f * r <= fabsf(x));
  int s = (x > 0.0f) ? 1 : ((x < 0.0f) ? -1 : 0);
  enc[j] = (uint8_t)(1 + (cond ? s : 0));
}

// ---------------------------------------------------------------------------
// Kernel 1b: one-time transpose w1 [HID][KIN] -> w1t [KIN][HID] (pure copy,
// bit-exact values; makes B rows contiguous for scalar loads).
// ---------------------------------------------------------------------------
__global__ __launch_bounds__(256) void transpose_kernel(const float* __restrict__ w1,
                                                        float* __restrict__ w1t) {
  int idx = blockIdx.x * blockDim.x + threadIdx.x;
  if (idx >= KIN * HID) return;
  int k = idx / HID, n = idx % HID;
  w1t[idx] = w1[(size_t)n * KIN + k];
}

// ---------------------------------------------------------------------------
// Kernel 2: panel partial Pz[b,j] for panel z = blockIdx.z.
// BM=512 (4 waves x 128 rows; lane owns rows r0=wv*128+lane, r0+64).
// BN=32: lane computes ALL 32 cols (B wave-uniform -> SGPR s_loads).
// BK=16: As u8 row-major [2][512][16] staged per-wave via gload_lds
// (wave stages ONLY its own strip -> no __syncthreads anywhere).
// Per 16-kk tile/lane: 2x contiguous ds_read_b128 (A), 0 LDS for B.
// Per kk: 2 cvt + 64 v_fmac (SGPR b). Panels 0,1: 16 full tiles + 8-kk tail.
// ---------------------------------------------------------------------------
#define BM 512
#define BN 32
#define BK 16

typedef uint32_t u32;

__device__ __forceinline__ float cvt_ub(u32 x, int i) {
  return (float)((x >> (8 * i)) & 0xffu);   // folds to v_cvt_f32_ubyte_i
}

// async global->LDS, 4B/lane: LDS dest = base + lane*4; source per-lane.
__device__ __forceinline__ void gload4(const void* g, void* l) {
  __builtin_amdgcn_global_load_lds(
      (const __attribute__((address_space(1))) void*)g,
      (__attribute__((address_space(3))) void*)l, 4, 0, 0);
}

__global__ __launch_bounds__(256) void gemm_kernel(const uint8_t* __restrict__ enc,
                                                   const float* __restrict__ w1t,
                                                   float* __restrict__ gp) {
  __shared__ uint8_t As[2][BM * BK];    // 2 x 8 KB
  const int panel  = blockIdx.z;
  const int kstart = panel * 264;
  const bool htail = (panel != 2);      // 264 = 16*16 + 8
  const int m0 = blockIdx.x * BM;
  const int n0 = blockIdx.y * BN;
  const int t  = threadIdx.x;
  const int lane = t & 63;
  const int wv   = t >> 6;

  // staging: wave wv stages its own 128 rows (2 KB) = 8 gload4 instrs.
  // instr q, lane i -> LDS byte wv*2048 + q*256 + i*4
  //   = row wv*128 + 16q + (i>>2), k-bytes (i&3)*4 .. +3
  const uint8_t* a_src = enc + (size_t)(m0 + wv * 128 + (lane >> 2)) * KIN
                         + kstart + (lane & 3) * 4;

  // rows owned by this lane
  const int r0 = wv * 128 + lane;       // and r0 + 64

  float acc0[32], acc1[32];
#pragma unroll
  for (int c = 0; c < 32; c++) { acc0[c] = 0.0f; acc1[c] = 0.0f; }

#define ISSUE(P, TILE)                                                    \
  {                                                                       \
    _Pragma("unroll")                                                     \
    for (int q = 0; q < 8; q++)                                           \
      gload4(a_src + (size_t)(TILE) * BK + (size_t)(16 * q) * KIN,        \
             &As[P][wv * 2048 + q * 256]);                                \
  }

  // ---- prologue: stage tile 0 into buffer 0 (own strip only) ----
  ISSUE(0, 0)

  int p = 0;
  for (int tile = 0; tile < 16; tile++) {
    // issue next tile into the other buffer (incl. tail tile for panels 0,1)
    if (tile < 15) { ISSUE(p ^ 1, tile + 1) }
    else if (htail) { ISSUE(p ^ 1, 16) }
    // A fragment: 2 contiguous b128 (compiler inserts the vmcnt wait)
    uint4 s0 = *(const uint4*)&As[p][(size_t)r0 * 16];
    uint4 s1 = *(const uint4*)&As[p][(size_t)(r0 + 64) * 16];
    const float* tb = w1t + (size_t)(kstart + tile * BK) * HID + n0;
#pragma unroll
    for (int kk = 0; kk < 16; kk++) {
      const u32 wa0[4] = {s0.x, s0.y, s0.z, s0.w};
      const u32 wa1[4] = {s1.x, s1.y, s1.z, s1.w};
      float a0 = cvt_ub(wa0[kk >> 2], kk & 3);
      float a1 = cvt_ub(wa1[kk >> 2], kk & 3);
      const float* brow = tb + (size_t)kk * HID;   // wave-uniform -> s_load
#pragma unroll
      for (int c = 0; c < 32; c++) {
        float b = brow[c];
        acc0[c] = __builtin_fmaf(a0, b, acc0[c]);  // exact product => ==mul+add
        acc1[c] = __builtin_fmaf(a1, b, acc1[c]);
      }
    }
    p ^= 1;
  }
  if (htail) {   // tail: k 256..263 of this panel (8 kk), ascending chain
    uint4 s0 = *(const uint4*)&As[p][(size_t)r0 * 16];
    uint4 s1 = *(const uint4*)&As[p][(size_t)(r0 + 64) * 16];
    const float* tb = w1t + (size_t)(kstart + 256) * HID + n0;
#pragma unroll
    for (int kk = 0; kk < 8; kk++) {
      const u32 wa0[2] = {s0.x, s0.y};
      const u32 wa1[2] = {s1.x, s1.y};
      float a0 = cvt_ub(wa0[kk >> 2], kk & 3);
      float a1 = cvt_ub(wa1[kk >> 2], kk & 3);
      const float* brow = tb + (size_t)kk * HID;
#pragma unroll
      for (int c = 0; c < 32; c++) {
        float b = brow[c];
        acc0[c] = __builtin_fmaf(a0, b, acc0[c]);
        acc1[c] = __builtin_fmaf(a1, b, acc1[c]);
      }
    }
  }
#undef ISSUE

  // epilogue: write RAW panel partial (combine happens in update_kernel)
  const size_t GS = (size_t)BSZ * HID;
  float* o0 = gp + (size_t)panel * GS + (size_t)(m0 + r0) * HID + n0;
  float* o1 = o0 + (size_t)64 * HID;
#pragma unroll
  for (int c = 0; c < 32; c += 4) {
    float4 v0 = {acc0[c], acc0[c + 1], acc0[c + 2], acc0[c + 3]};
    float4 v1 = {acc1[c], acc1[c + 1], acc1[c + 2], acc1[c + 3]};
    *(float4*)(o0 + c) = v0;
    *(float4*)(o1 + c) = v1;
  }
}

// ---------------------------------------------------------------------------
// Kernel 3: combine panels (exact Eigen order) + membrane update + spike +
// mem2 accumulation.
// g = 0.5 * rn(rn(P0+P1) + P2)   (0.5 exact)
// m = rn(rn(0.95f*mem) + rn(0.05f*g)) — mul/mul/add; products NOT exact here,
// so FMA contraction would change bits — keep split __fmul_rn/__fadd_rn.
// ---------------------------------------------------------------------------
__global__ __launch_bounds__(256) void update_kernel(const float* __restrict__ gp,
                                                     float* __restrict__ mem1,
                                                     const float* __restrict__ w2,
                                                     float* __restrict__ mem2) {
  __shared__ float w2s[NOUT * HID];   // 32 KB
  for (int i = threadIdx.x; i < NOUT * HID; i += 256) w2s[i] = w2[i];
  __syncthreads();

  const int wave = threadIdx.x / 64;
  const int lane = threadIdx.x % 64;
  const int b = blockIdx.x * 4 + wave;

  const size_t GS = (size_t)BSZ * HID;
  const float* g0 = gp + (size_t)b * HID;
  const float* g1 = g0 + GS;
  const float* g2 = g1 + GS;
  float* mrow = mem1 + (size_t)b * HID;

  float acc[NOUT];
#pragma unroll
  for (int i = 0; i < NOUT; i++) acc[i] = 0.0f;

  for (int j = lane; j < HID; j += 64) {
    float gs = __fmul_rn(0.5f, __fadd_rn(__fadd_rn(g0[j], g1[j]), g2[j]));
    float m = __fadd_rn(__fmul_rn(0.95f, mrow[j]), __fmul_rn(0.05f, gs));
    bool spike = __fadd_rn(m, -1.0f) > 0.0f;
    mrow[j] = spike ? __fadd_rn(m, -1.0f) : m;
    if (spike) {
#pragma unroll
      for (int i = 0; i < NOUT; i++) acc[i] += w2s[i * HID + j];
    }
  }
  // mem2 never feeds back into spike decisions: reduction-order noise ~1e-7
  // << 3.6e-3 threshold, no need to replicate ref's order here.
#pragma unroll
  for (int i = 0; i < NOUT; i++) {
    float v = acc[i];
    for (int off = 32; off > 0; off >>= 1) v += __shfl_down(v, off);
    if (lane == 0) mem2[(size_t)b * NOUT + i] += v;
  }
}

// ---------------------------------------------------------------------------
// Kernel 4: out = mem2 / num_steps
// ---------------------------------------------------------------------------
__global__ __launch_bounds__(256) void finalize_kernel(const float* __restrict__ mem2,
                                                       const int* __restrict__ ns,
                                                       float* __restrict__ out) {
  int i = blockIdx.x * blockDim.x + threadIdx.x;
  if (i < BSZ * NOUT) out[i] = mem2[i] / (float)(*ns);
}

// ---------------------------------------------------------------------------
extern "C" void kernel_launch(void* const* d_in, const int* in_sizes, int n_in,
                              void* d_out, int out_size, void* d_ws, size_t ws_size,
                              hipStream_t stream) {
  const float* inp = (const float*)d_in[0];
  const float* w1  = (const float*)d_in[1];
  const float* w2  = (const float*)d_in[2];
  const int*   dns = (const int*)d_in[3];
  float* out = (float*)d_out;

  char* ws = (char*)d_ws;
  size_t off = 0;
  uint8_t* enc = (uint8_t*)(ws + off);  off += (size_t)BSZ * KIN;          // 6.4 MB
  off = (off + 255) & ~(size_t)255;
  float* w1t  = (float*)(ws + off);     off += (size_t)KIN * HID * 4;      // 2.5 MB
  float* gp   = (float*)(ws + off);     off += (size_t)3 * BSZ * HID * 4;  // 78.6 MB
  float* mem1 = (float*)(ws + off);     off += (size_t)BSZ * HID * 4;      // 26.2 MB
  float* mem2 = (float*)(ws + off);     off += (size_t)BSZ * NOUT * 4;     // 0.33 MB

  (void)hipMemsetAsync(mem1, 0, (size_t)BSZ * HID * 4, stream);
  (void)hipMemsetAsync(mem2, 0, (size_t)BSZ * NOUT * 4, stream);

  // one-time transpose (w1 constant across steps)
  transpose_kernel<<<(KIN * HID + 255) / 256, 256, 0, stream>>>(w1, w1t);

  // Step keys: partitionable split — key_t = threefry((0,42), (0,t)).
  uint32_t keys[NSTEP][2];
  for (int t = 0; t < NSTEP; t++)
    threefry2x32(0u, 42u, 0u, (uint32_t)t, &keys[t][0], &keys[t][1]);

  const int n_elem = BSZ * KIN;
  for (int t = 0; t < NSTEP; t++) {
    enc_kernel<<<(n_elem + 255) / 256, 256, 0, stream>>>(inp, enc, keys[t][0], keys[t][1]);
    gemm_kernel<<<dim3(BSZ / BM, HID / BN, 3), 256, 0, stream>>>(enc, w1t, gp);
    update_kernel<<<BSZ / 4, 256, 0, stream>>>(gp, mem1, w2, mem2);
  }
  finalize_kernel<<<(BSZ * NOUT + 255) / 256, 256, 0, stream>>>(mem2, dns, out);
}

// Round 16
// 4559.352 us; speedup vs baseline: 1.1730x; 1.1730x over previous
//
#include <hip/hip_runtime.h>
#include <cstdint>

// ---------------------------------------------------------------------------
// Threefry-2x32 (JAX partitionable-mode compatible), host + device.
// ---------------------------------------------------------------------------
__host__ __device__ inline uint32_t tf_rotl32(uint32_t x, uint32_t r) {
  return (x << r) | (x >> (32u - r));
}

__host__ __device__ inline void threefry2x32(uint32_t k0, uint32_t k1,
                                             uint32_t x0, uint32_t x1,
                                             uint32_t* o0, uint32_t* o1) {
  uint32_t ks0 = k0, ks1 = k1, ks2 = k0 ^ k1 ^ 0x1BD11BDAu;
  x0 += ks0; x1 += ks1;
#define TF_R(r) { x0 += x1; x1 = tf_rotl32(x1, r); x1 ^= x0; }
  TF_R(13) TF_R(15) TF_R(26) TF_R(6)
  x0 += ks1; x1 += ks2 + 1u;
  TF_R(17) TF_R(29) TF_R(16) TF_R(24)
  x0 += ks2; x1 += ks0 + 2u;
  TF_R(13) TF_R(15) TF_R(26) TF_R(6)
  x0 += ks0; x1 += ks1 + 3u;
  TF_R(17) TF_R(29) TF_R(16) TF_R(24)
  x0 += ks1; x1 += ks2 + 4u;
  TF_R(13) TF_R(15) TF_R(26) TF_R(6)
  x0 += ks2; x1 += ks0 + 5u;
#undef TF_R
  *o0 = x0; *o1 = x1;
}

// ---------------------------------------------------------------------------
// Problem dims
// ---------------------------------------------------------------------------
#define BSZ   8192
#define KIN   784
#define HID   800
#define NOUT  10
#define NSTEP 25

// R8: golden = Eigen gebp (AVX no-FMA jaxlib): k-panels [0,264) [264,528)
// [528,784), per k-step acc = rn(acc + rn(a*b)); C = 0.5*rn(rn(P0+P1)+P2).
// R9: a in {0,1,2} makes every product exact, so fmaf == mul+add bit-exactly.
// R17: panel-split -> best classic config 158us (R9).
// R20-R23: wall pinned 157-165 across 5 structures (both pipes ~122-125us).
// R24 (R15): B-in-SGPR + A gload_lds: VALU shrank to ~82us (proven: 0.456 x
//   180) but occupancy collapsed to 25% (1200 big blocks, VGPR 72) ->
//   SMEM/A-wait latency exposed -> 180us.
// R25 (this round): SAME pipes, fix parallelism only. 1 row/lane: BM=256
//   (4 waves x 64 rows), grid 2400 blocks / 9600 waves -> 8 waves/SIMD
//   (acc 32 VGPR, total ~56). Zero barriers (wave-private strips; LLVM
//   scoreboard emits counted vmcnt, no barrier drain). A strips: 16-row
//   256B groups padded to 272B stride -> frag b128 2-way banks (free).
//   VALU ~69us (32 fmac + 1 cvt per kk per 2048 MACs); LDS ~6us.
//   Predict gemm 180 -> 95-125, occ 25 -> 60-95; falsifier: >=150 at
//   occ>=60 -> SMEM-throughput capped -> revert to R9-best and declare.
// ---------------------------------------------------------------------------

// ---------------------------------------------------------------------------
// Kernel 1: Poisson encoding (JAX-faithful: truncated 2^-23 grid).
// enc = temp + 1 in {0,1,2}; sp = 0.5*enc (exact power-of-2 relation).
// ---------------------------------------------------------------------------
__global__ __launch_bounds__(256) void enc_kernel(const float* __restrict__ inp,
                                                  uint8_t* __restrict__ enc,
                                                  uint32_t k0, uint32_t k1) {
  int j = blockIdx.x * blockDim.x + threadIdx.x;
  if (j >= BSZ * KIN) return;
  uint32_t o0, o1;
  threefry2x32(k0, k1, 0u, (uint32_t)j, &o0, &o1);
  uint32_t bits = o0 ^ o1;
  float r = __uint_as_float((bits >> 9) | 0x3f800000u) - 1.0f;
  float x = inp[j];
  bool cond = (2.0f * r <= fabsf(x));
  int s = (x > 0.0f) ? 1 : ((x < 0.0f) ? -1 : 0);
  enc[j] = (uint8_t)(1 + (cond ? s : 0));
}

// ---------------------------------------------------------------------------
// Kernel 1b: one-time transpose w1 [HID][KIN] -> w1t [KIN][HID] (pure copy,
// bit-exact values; makes B rows contiguous for scalar loads).
// ---------------------------------------------------------------------------
__global__ __launch_bounds__(256) void transpose_kernel(const float* __restrict__ w1,
                                                        float* __restrict__ w1t) {
  int idx = blockIdx.x * blockDim.x + threadIdx.x;
  if (idx >= KIN * HID) return;
  int k = idx / HID, n = idx % HID;
  w1t[idx] = w1[(size_t)n * KIN + k];
}

// ---------------------------------------------------------------------------
// Kernel 2: panel partial Pz[b,j] for panel z = blockIdx.z.
// BM=256 (4 waves x 64 rows; lane owns row r0 = wv*64 + lane).
// BN=32: lane computes ALL 32 cols (B wave-uniform -> SGPR s_loads).
// BK=16: As u8 staged per-wave via gload_lds into 16-row 256B groups,
// group stride 272B (pad 16B) -> frag ds_read_b128 2-way banks.
// Zero __syncthreads: each wave stages + reads ONLY its own strip.
// Per kk: 1 cvt + 32 v_fmac (SGPR b). Panels 0,1: 16 full tiles + 8-kk tail.
// ---------------------------------------------------------------------------
#define BM 256
#define BN 32
#define BK 16
#define GSTRIDE 272                   // bytes per 16-row group (256 + 16 pad)
#define WSTRIDE (4 * GSTRIDE)         // 1088 bytes per wave strip
#define BUFSZ   (4 * WSTRIDE)         // 4352 bytes per buffer

typedef uint32_t u32;

__device__ __forceinline__ float cvt_ub(u32 x, int i) {
  return (float)((x >> (8 * i)) & 0xffu);   // folds to v_cvt_f32_ubyte_i
}

// async global->LDS, 4B/lane: LDS dest = base + lane*4; source per-lane.
__device__ __forceinline__ void gload4(const void* g, void* l) {
  __builtin_amdgcn_global_load_lds(
      (const __attribute__((address_space(1))) void*)g,
      (__attribute__((address_space(3))) void*)l, 4, 0, 0);
}

__global__ __launch_bounds__(256) void gemm_kernel(const uint8_t* __restrict__ enc,
                                                   const float* __restrict__ w1t,
                                                   float* __restrict__ gp) {
  __shared__ uint8_t As[2][BUFSZ];      // 2 x 4.25 KB
  const int panel  = blockIdx.z;
  const int kstart = panel * 264;
  const bool htail = (panel != 2);      // 264 = 16*16 + 8
  const int m0 = blockIdx.x * BM;
  const int n0 = blockIdx.y * BN;
  const int t  = threadIdx.x;
  const int lane = t & 63;
  const int wv   = t >> 6;

  // staging: wave wv stages its own 64 rows = 4 gload4 instrs.
  // instr q, lane i -> LDS byte wv*WSTRIDE + q*GSTRIDE + i*4
  //   = row wv*64 + q*16 + (i>>2), k-bytes (i&3)*4 .. +3
  const uint8_t* a_src = enc + (size_t)(m0 + wv * 64 + (lane >> 2)) * KIN
                         + kstart + (lane & 3) * 4;

  // row owned by this lane + its LDS read offset (group-padded)
  const int r0  = wv * 64 + lane;
  const int ard = wv * WSTRIDE + (lane >> 4) * GSTRIDE + (lane & 15) * 16;

  float acc[32];
#pragma unroll
  for (int c = 0; c < 32; c++) acc[c] = 0.0f;

#define ISSUE(P, TILE)                                                    \
  {                                                                       \
    _Pragma("unroll")                                                     \
    for (int q = 0; q < 4; q++)                                           \
      gload4(a_src + (size_t)(TILE) * BK + (size_t)(16 * q) * KIN,        \
             &As[P][wv * WSTRIDE + q * GSTRIDE]);                         \
  }

  // ---- prologue: stage tile 0 into buffer 0 (own strip only) ----
  ISSUE(0, 0)

  int p = 0;
  for (int tile = 0; tile < 16; tile++) {
    // issue next tile into the other buffer (incl. tail tile for panels 0,1)
    if (tile < 15) { ISSUE(p ^ 1, tile + 1) }
    else if (htail) { ISSUE(p ^ 1, 16) }
    // A fragment: 1 b128 (own row; counted vmcnt by scoreboard, no barrier)
    uint4 s0 = *(const uint4*)&As[p][ard];
    const u32 w[4] = {s0.x, s0.y, s0.z, s0.w};
    const float* tb = w1t + (size_t)(kstart + tile * BK) * HID + n0;
#pragma unroll
    for (int kk = 0; kk < 16; kk++) {
      float a0 = cvt_ub(w[kk >> 2], kk & 3);
      const float* brow = tb + (size_t)kk * HID;   // wave-uniform -> s_load
#pragma unroll
      for (int c = 0; c < 32; c++)
        acc[c] = __builtin_fmaf(a0, brow[c], acc[c]);  // exact product
    }
    p ^= 1;
  }
  if (htail) {   // tail: k 256..263 of this panel (8 kk), ascending chain
    uint4 s0 = *(const uint4*)&As[p][ard];
    const u32 w[2] = {s0.x, s0.y};
    const float* tb = w1t + (size_t)(kstart + 256) * HID + n0;
#pragma unroll
    for (int kk = 0; kk < 8; kk++) {
      float a0 = cvt_ub(w[kk >> 2], kk & 3);
      const float* brow = tb + (size_t)kk * HID;
#pragma unroll
      for (int c = 0; c < 32; c++)
        acc[c] = __builtin_fmaf(a0, brow[c], acc[c]);
    }
  }
#undef ISSUE

  // epilogue: write RAW panel partial (combine happens in update_kernel)
  const size_t GS = (size_t)BSZ * HID;
  float* o0 = gp + (size_t)panel * GS + (size_t)(m0 + r0) * HID + n0;
#pragma unroll
  for (int c = 0; c < 32; c += 4) {
    float4 v0 = {acc[c], acc[c + 1], acc[c + 2], acc[c + 3]};
    *(float4*)(o0 + c) = v0;
  }
}

// ---------------------------------------------------------------------------
// Kernel 3: combine panels (exact Eigen order) + membrane update + spike +
// mem2 accumulation.
// g = 0.5 * rn(rn(P0+P1) + P2)   (0.5 exact)
// m = rn(rn(0.95f*mem) + rn(0.05f*g)) — mul/mul/add; products NOT exact here,
// so FMA contraction would change bits — keep split __fmul_rn/__fadd_rn.
// ---------------------------------------------------------------------------
__global__ __launch_bounds__(256) void update_kernel(const float* __restrict__ gp,
                                                     float* __restrict__ mem1,
                                                     const float* __restrict__ w2,
                                                     float* __restrict__ mem2) {
  __shared__ float w2s[NOUT * HID];   // 32 KB
  for (int i = threadIdx.x; i < NOUT * HID; i += 256) w2s[i] = w2[i];
  __syncthreads();

  const int wave = threadIdx.x / 64;
  const int lane = threadIdx.x % 64;
  const int b = blockIdx.x * 4 + wave;

  const size_t GS = (size_t)BSZ * HID;
  const float* g0 = gp + (size_t)b * HID;
  const float* g1 = g0 + GS;
  const float* g2 = g1 + GS;
  float* mrow = mem1 + (size_t)b * HID;

  float acc[NOUT];
#pragma unroll
  for (int i = 0; i < NOUT; i++) acc[i] = 0.0f;

  for (int j = lane; j < HID; j += 64) {
    float gs = __fmul_rn(0.5f, __fadd_rn(__fadd_rn(g0[j], g1[j]), g2[j]));
    float m = __fadd_rn(__fmul_rn(0.95f, mrow[j]), __fmul_rn(0.05f, gs));
    bool spike = __fadd_rn(m, -1.0f) > 0.0f;
    mrow[j] = spike ? __fadd_rn(m, -1.0f) : m;
    if (spike) {
#pragma unroll
      for (int i = 0; i < NOUT; i++) acc[i] += w2s[i * HID + j];
    }
  }
  // mem2 never feeds back into spike decisions: reduction-order noise ~1e-7
  // << 3.6e-3 threshold, no need to replicate ref's order here.
#pragma unroll
  for (int i = 0; i < NOUT; i++) {
    float v = acc[i];
    for (int off = 32; off > 0; off >>= 1) v += __shfl_down(v, off);
    if (lane == 0) mem2[(size_t)b * NOUT + i] += v;
  }
}

// ---------------------------------------------------------------------------
// Kernel 4: out = mem2 / num_steps
// ---------------------------------------------------------------------------
__global__ __launch_bounds__(256) void finalize_kernel(const float* __restrict__ mem2,
                                                       const int* __restrict__ ns,
                                                       float* __restrict__ out) {
  int i = blockIdx.x * blockDim.x + threadIdx.x;
  if (i < BSZ * NOUT) out[i] = mem2[i] / (float)(*ns);
}

// ---------------------------------------------------------------------------
extern "C" void kernel_launch(void* const* d_in, const int* in_sizes, int n_in,
                              void* d_out, int out_size, void* d_ws, size_t ws_size,
                              hipStream_t stream) {
  const float* inp = (const float*)d_in[0];
  const float* w1  = (const float*)d_in[1];
  const float* w2  = (const float*)d_in[2];
  const int*   dns = (const int*)d_in[3];
  float* out = (float*)d_out;

  char* ws = (char*)d_ws;
  size_t off = 0;
  uint8_t* enc = (uint8_t*)(ws + off);  off += (size_t)BSZ * KIN;          // 6.4 MB
  off = (off + 255) & ~(size_t)255;
  float* w1t  = (float*)(ws + off);     off += (size_t)KIN * HID * 4;      // 2.5 MB
  float* gp   = (float*)(ws + off);     off += (size_t)3 * BSZ * HID * 4;  // 78.6 MB
  float* mem1 = (float*)(ws + off);     off += (size_t)BSZ * HID * 4;      // 26.2 MB
  float* mem2 = (float*)(ws + off);     off += (size_t)BSZ * NOUT * 4;     // 0.33 MB

  (void)hipMemsetAsync(mem1, 0, (size_t)BSZ * HID * 4, stream);
  (void)hipMemsetAsync(mem2, 0, (size_t)BSZ * NOUT * 4, stream);

  // one-time transpose (w1 constant across steps)
  transpose_kernel<<<(KIN * HID + 255) / 256, 256, 0, stream>>>(w1, w1t);

  // Step keys: partitionable split — key_t = threefry((0,42), (0,t)).
  uint32_t keys[NSTEP][2];
  for (int t = 0; t < NSTEP; t++)
    threefry2x32(0u, 42u, 0u, (uint32_t)t, &keys[t][0], &keys[t][1]);

  const int n_elem = BSZ * KIN;
  for (int t = 0; t < NSTEP; t++) {
    enc_kernel<<<(n_elem + 255) / 256, 256, 0, stream>>>(inp, enc, keys[t][0], keys[t][1]);
    gemm_kernel<<<dim3(BSZ / BM, HID / BN, 3), 256, 0, stream>>>(enc, w1t, gp);
    update_kernel<<<BSZ / 4, 256, 0, stream>>>(gp, mem1, w2, mem2);
  }
  finalize_kernel<<<(BSZ * NOUT + 255) / 256, 256, 0, stream>>>(mem2, dns, out);
}

// Round 17
// 4292.549 us; speedup vs baseline: 1.2460x; 1.0622x over previous
//
#include <hip/hip_runtime.h>
#include <cstdint>

// ---------------------------------------------------------------------------
// Threefry-2x32 (JAX partitionable-mode compatible), host + device.
// ---------------------------------------------------------------------------
__host__ __device__ inline uint32_t tf_rotl32(uint32_t x, uint32_t r) {
  return (x << r) | (x >> (32u - r));
}

__host__ __device__ inline void threefry2x32(uint32_t k0, uint32_t k1,
                                             uint32_t x0, uint32_t x1,
                                             uint32_t* o0, uint32_t* o1) {
  uint32_t ks0 = k0, ks1 = k1, ks2 = k0 ^ k1 ^ 0x1BD11BDAu;
  x0 += ks0; x1 += ks1;
#define TF_R(r) { x0 += x1; x1 = tf_rotl32(x1, r); x1 ^= x0; }
  TF_R(13) TF_R(15) TF_R(26) TF_R(6)
  x0 += ks1; x1 += ks2 + 1u;
  TF_R(17) TF_R(29) TF_R(16) TF_R(24)
  x0 += ks2; x1 += ks0 + 2u;
  TF_R(13) TF_R(15) TF_R(26) TF_R(6)
  x0 += ks0; x1 += ks1 + 3u;
  TF_R(17) TF_R(29) TF_R(16) TF_R(24)
  x0 += ks1; x1 += ks2 + 4u;
  TF_R(13) TF_R(15) TF_R(26) TF_R(6)
  x0 += ks2; x1 += ks0 + 5u;
#undef TF_R
  *o0 = x0; *o1 = x1;
}

// ---------------------------------------------------------------------------
// Problem dims
// ---------------------------------------------------------------------------
#define BSZ   8192
#define KIN   784
#define HID   800
#define NOUT  10
#define NSTEP 25

// R8: golden = Eigen gebp (AVX no-FMA jaxlib): k-panels [0,264) [264,528)
// [528,784), per k-step acc = rn(acc + rn(a*b)); C = 0.5*rn(rn(P0+P1)+P2).
// R9: a in {0,1,2} makes every product exact, so fmaf == mul+add bit-exactly.
// R17: panel-split; best classic config 158us (R9).
// R24/R25: B-in-SGPR proven (SGPR=112, VALU 122->77us); R16 = 147.7us,
//   occ 49%, VALUBusy 52% -> ~71us stall: (a) 2x s_load_dwordx16/kk chains
//   (only ~2 kk SMEM prefetch at 32 SGPR/kk); (b) 627K A-frag bank-conflict
//   cycles; (c) LDS round-trip for A is POINTLESS (A is lane-private in the
//   1-row/lane decomposition; gload_lds source pattern == direct per-lane
//   loads in segment granularity).
// R26 (this round): (1) NO LDS — lane global_load_dwordx4's its own row's
//   16 k-bytes per tile, double-buffered in regs (enc is L2/L3-resident;
//   ~9us L2 BW). (2) BN 32->16: one s_load_dwordx16/kk, half SGPR pressure
//   -> 2x deeper SMEM prefetch; grid 32x50x3 = 4800 blocks/19200 waves;
//   acc 16 VGPR -> 8 waves/SIMD. VALU floor ~69us unchanged.
//   Predict gemm 147.7 -> 105-130; falsifier >=140 -> VMEM-scatter bound,
//   revert to LDS staging and declare ~145 floor.
// ---------------------------------------------------------------------------

// ---------------------------------------------------------------------------
// Kernel 1: Poisson encoding (JAX-faithful: truncated 2^-23 grid).
// enc = temp + 1 in {0,1,2}; sp = 0.5*enc (exact power-of-2 relation).
// ---------------------------------------------------------------------------
__global__ __launch_bounds__(256) void enc_kernel(const float* __restrict__ inp,
                                                  uint8_t* __restrict__ enc,
                                                  uint32_t k0, uint32_t k1) {
  int j = blockIdx.x * blockDim.x + threadIdx.x;
  if (j >= BSZ * KIN) return;
  uint32_t o0, o1;
  threefry2x32(k0, k1, 0u, (uint32_t)j, &o0, &o1);
  uint32_t bits = o0 ^ o1;
  float r = __uint_as_float((bits >> 9) | 0x3f800000u) - 1.0f;
  float x = inp[j];
  bool cond = (2.0f * r <= fabsf(x));
  int s = (x > 0.0f) ? 1 : ((x < 0.0f) ? -1 : 0);
  enc[j] = (uint8_t)(1 + (cond ? s : 0));
}

// ---------------------------------------------------------------------------
// Kernel 1b: one-time transpose w1 [HID][KIN] -> w1t [KIN][HID] (pure copy,
// bit-exact values; makes B rows contiguous for scalar loads).
// ---------------------------------------------------------------------------
__global__ __launch_bounds__(256) void transpose_kernel(const float* __restrict__ w1,
                                                        float* __restrict__ w1t) {
  int idx = blockIdx.x * blockDim.x + threadIdx.x;
  if (idx >= KIN * HID) return;
  int k = idx / HID, n = idx % HID;
  w1t[idx] = w1[(size_t)n * KIN + k];
}

// ---------------------------------------------------------------------------
// Kernel 2: panel partial Pz[b,j] for panel z = blockIdx.z.
// BM=256 (4 waves x 64 rows; lane owns exactly one row). BN=16: lane
// computes all 16 cols (B wave-uniform -> one s_load_dwordx16 per kk).
// NO LDS: lane loads its own row's 16 k-bytes per tile (dwordx4),
// double-buffered in registers. Zero barriers.
// Per kk: 1 cvt + 16 v_fmac (SGPR b). Panels 0,1: 16 full tiles + 8-kk tail
// (tail prefetched as a 16B read of bytes 256..271 of the panel slice —
// in-bounds of the 784B row for panels 0,1; only first 8 bytes used).
// ---------------------------------------------------------------------------
#define BM 256
#define BN 16
#define BK 16

typedef uint32_t u32;

__device__ __forceinline__ float cvt_ub(u32 x, int i) {
  return (float)((x >> (8 * i)) & 0xffu);   // folds to v_cvt_f32_ubyte_i
}

__global__ __launch_bounds__(256) void gemm_kernel(const uint8_t* __restrict__ enc,
                                                   const float* __restrict__ w1t,
                                                   float* __restrict__ gp) {
  const int panel  = blockIdx.z;
  const int kstart = panel * 264;
  const bool htail = (panel != 2);      // 264 = 16*16 + 8
  const int m0 = blockIdx.x * BM;
  const int n0 = blockIdx.y * BN;
  const int t  = threadIdx.x;
  const int lane = t & 63;
  const int wv   = t >> 6;

  // lane-private A row
  const int r0 = wv * 64 + lane;
  const uint8_t* arow = enc + (size_t)(m0 + r0) * KIN + kstart;

  float acc[16];
#pragma unroll
  for (int c = 0; c < 16; c++) acc[c] = 0.0f;

  const int nld = htail ? 17 : 16;      // #16B loads (17th = tail bytes)

  uint4 acur = *(const uint4*)(arow);   // tile 0
  uint4 anext;

  for (int tile = 0; tile < 16; tile++) {
    // prefetch next 16B chunk (tile or tail) while computing this tile
    if (tile + 1 < nld)
      anext = *(const uint4*)(arow + (size_t)(tile + 1) * BK);
    const u32 w[4] = {acur.x, acur.y, acur.z, acur.w};
    const float* tb = w1t + (size_t)(kstart + tile * BK) * HID + n0;
#pragma unroll
    for (int kk = 0; kk < 16; kk++) {
      float a0 = cvt_ub(w[kk >> 2], kk & 3);
      const float* brow = tb + (size_t)kk * HID;   // wave-uniform -> s_load
#pragma unroll
      for (int c = 0; c < 16; c++)
        acc[c] = __builtin_fmaf(a0, brow[c], acc[c]);  // exact product
    }
    acur = anext;
  }
  if (htail) {   // tail: k 256..263 of this panel (8 kk), ascending chain
    const u32 w[2] = {acur.x, acur.y};
    const float* tb = w1t + (size_t)(kstart + 256) * HID + n0;
#pragma unroll
    for (int kk = 0; kk < 8; kk++) {
      float a0 = cvt_ub(w[kk >> 2], kk & 3);
      const float* brow = tb + (size_t)kk * HID;
#pragma unroll
      for (int c = 0; c < 16; c++)
        acc[c] = __builtin_fmaf(a0, brow[c], acc[c]);
    }
  }

  // epilogue: write RAW panel partial (combine happens in update_kernel)
  const size_t GS = (size_t)BSZ * HID;
  float* o0 = gp + (size_t)panel * GS + (size_t)(m0 + r0) * HID + n0;
#pragma unroll
  for (int c = 0; c < 16; c += 4) {
    float4 v0 = {acc[c], acc[c + 1], acc[c + 2], acc[c + 3]};
    *(float4*)(o0 + c) = v0;
  }
}

// ---------------------------------------------------------------------------
// Kernel 3: combine panels (exact Eigen order) + membrane update + spike +
// mem2 accumulation.
// g = 0.5 * rn(rn(P0+P1) + P2)   (0.5 exact)
// m = rn(rn(0.95f*mem) + rn(0.05f*g)) — mul/mul/add; products NOT exact here,
// so FMA contraction would change bits — keep split __fmul_rn/__fadd_rn.
// ---------------------------------------------------------------------------
__global__ __launch_bounds__(256) void update_kernel(const float* __restrict__ gp,
                                                     float* __restrict__ mem1,
                                                     const float* __restrict__ w2,
                                                     float* __restrict__ mem2) {
  __shared__ float w2s[NOUT * HID];   // 32 KB
  for (int i = threadIdx.x; i < NOUT * HID; i += 256) w2s[i] = w2[i];
  __syncthreads();

  const int wave = threadIdx.x / 64;
  const int lane = threadIdx.x % 64;
  const int b = blockIdx.x * 4 + wave;

  const size_t GS = (size_t)BSZ * HID;
  const float* g0 = gp + (size_t)b * HID;
  const float* g1 = g0 + GS;
  const float* g2 = g1 + GS;
  float* mrow = mem1 + (size_t)b * HID;

  float acc[NOUT];
#pragma unroll
  for (int i = 0; i < NOUT; i++) acc[i] = 0.0f;

  for (int j = lane; j < HID; j += 64) {
    float gs = __fmul_rn(0.5f, __fadd_rn(__fadd_rn(g0[j], g1[j]), g2[j]));
    float m = __fadd_rn(__fmul_rn(0.95f, mrow[j]), __fmul_rn(0.05f, gs));
    bool spike = __fadd_rn(m, -1.0f) > 0.0f;
    mrow[j] = spike ? __fadd_rn(m, -1.0f) : m;
    if (spike) {
#pragma unroll
      for (int i = 0; i < NOUT; i++) acc[i] += w2s[i * HID + j];
    }
  }
  // mem2 never feeds back into spike decisions: reduction-order noise ~1e-7
  // << 3.6e-3 threshold, no need to replicate ref's order here.
#pragma unroll
  for (int i = 0; i < NOUT; i++) {
    float v = acc[i];
    for (int off = 32; off > 0; off >>= 1) v += __shfl_down(v, off);
    if (lane == 0) mem2[(size_t)b * NOUT + i] += v;
  }
}

// ---------------------------------------------------------------------------
// Kernel 4: out = mem2 / num_steps
// ---------------------------------------------------------------------------
__global__ __launch_bounds__(256) void finalize_kernel(const float* __restrict__ mem2,
                                                       const int* __restrict__ ns,
                                                       float* __restrict__ out) {
  int i = blockIdx.x * blockDim.x + threadIdx.x;
  if (i < BSZ * NOUT) out[i] = mem2[i] / (float)(*ns);
}

// ---------------------------------------------------------------------------
extern "C" void kernel_launch(void* const* d_in, const int* in_sizes, int n_in,
                              void* d_out, int out_size, void* d_ws, size_t ws_size,
                              hipStream_t stream) {
  const float* inp = (const float*)d_in[0];
  const float* w1  = (const float*)d_in[1];
  const float* w2  = (const float*)d_in[2];
  const int*   dns = (const int*)d_in[3];
  float* out = (float*)d_out;

  char* ws = (char*)d_ws;
  size_t off = 0;
  uint8_t* enc = (uint8_t*)(ws + off);  off += (size_t)BSZ * KIN;          // 6.4 MB
  off = (off + 255) & ~(size_t)255;
  float* w1t  = (float*)(ws + off);     off += (size_t)KIN * HID * 4;      // 2.5 MB
  float* gp   = (float*)(ws + off);     off += (size_t)3 * BSZ * HID * 4;  // 78.6 MB
  float* mem1 = (float*)(ws + off);     off += (size_t)BSZ * HID * 4;      // 26.2 MB
  float* mem2 = (float*)(ws + off);     off += (size_t)BSZ * NOUT * 4;     // 0.33 MB

  (void)hipMemsetAsync(mem1, 0, (size_t)BSZ * HID * 4, stream);
  (void)hipMemsetAsync(mem2, 0, (size_t)BSZ * NOUT * 4, stream);

  // one-time transpose (w1 constant across steps)
  transpose_kernel<<<(KIN * HID + 255) / 256, 256, 0, stream>>>(w1, w1t);

  // Step keys: partitionable split — key_t = threefry((0,42), (0,t)).
  uint32_t keys[NSTEP][2];
  for (int t = 0; t < NSTEP; t++)
    threefry2x32(0u, 42u, 0u, (uint32_t)t, &keys[t][0], &keys[t][1]);

  const int n_elem = BSZ * KIN;
  for (int t = 0; t < NSTEP; t++) {
    enc_kernel<<<(n_elem + 255) / 256, 256, 0, stream>>>(inp, enc, keys[t][0], keys[t][1]);
    gemm_kernel<<<dim3(BSZ / BM, HID / BN, 3), 256, 0, stream>>>(enc, w1t, gp);
    update_kernel<<<BSZ / 4, 256, 0, stream>>>(gp, mem1, w2, mem2);
  }
  finalize_kernel<<<(BSZ * NOUT + 255) / 256, 256, 0, stream>>>(mem2, dns, out);
}